// Round 18
// baseline (300.419 us; speedup 1.0000x reference)
//
#include <hip/hip_runtime.h>
#include <hip/hip_bf16.h>

// GCN 2-layer forward, fp32 I/O. dinv folded into stored rows:
//   h1' = dinv * (x @ W1),  agg1 = dinv * (h1'[i] + sum_nbr h1'[s])
//   h2' = dinv * (relu(agg1+b1) @ W2),  out = dinv * (h2'[i] + sum h2'[s]) + b2
// so pull kernels are pure gather+add (no per-edge norm, no dinv reads).
// Packed 4B edge records; fixed-capacity bucketed CSR build with all
// per-node atomics in LDS; bf16 h/agg storage; MFMA bf16 GEMMs.
//
// ROUND 18 (= round-14..17 resubmission: four GPU-acquisition failures,
// no data). Diagnostic: banked ~286 us; pull128 (60 us) is closed at its
// fabric roofline (FETCH == 8-XCD compulsory floor, 3.75 TB/s random-256B
// ceiling), but it masks the other ~226 us in the top-5 profile window.
// This round splits pull128 into 4 sequential quarter-range dispatches
// (~15 us each, work-identical) purely to drop the profiling visibility
// threshold 60 -> ~15 us and surface the true #2/#3 kernels with
// counters. No other changes vs the banked config.
// Pipeline:
//  1) k_prep: W1,W2 -> bf16 transposed; bcur[b] = b*CAP (looped init)
//  2) k_bucket: partition packed {src,dloc} by dst>>8 into ebuf
//  3) k_bcsr:  per-bucket LDS stage -> hist -> scan -> deg/dinv/row_ptr
//              -> LDS-cursor scatter -> csr4 = src
//  4) h1' = dinv*(x @ W1) -> bf16                  (k_gemm1, MFMA)
//  5) aggb = dinv*(self+gather-sum of h1') -> bf16 (k_pull128 x4 ranges)
//  6) h2' = dinv*(relu(aggb+b1) @ W2) -> bf16      (k_gemm2, MFMA)
//  7) out = dinv*(self+gather-sum of h2') + b2     (k_pull64, 2 nodes/wave)

typedef short short8v __attribute__((ext_vector_type(8)));   // 8 bf16 (4 VGPRs)
typedef float f32x4   __attribute__((ext_vector_type(4)));   // MFMA acc
typedef float f32x2   __attribute__((ext_vector_type(2)));   // NT out store

#define BSHIFT 8           // bucket = dst >> 8 (span 256 nodes)
#define BSIZE  256
#define CAPSH  13          // per-bucket capacity 8192 (mean 4352, +58 sigma)
#define CAP    (1 << CAPSH)

// RNE fp32 -> bf16 (finite inputs)
__device__ __forceinline__ short f2bf(float f) {
    unsigned u = __float_as_uint(f);
    return (short)((u + 0x7fffu + ((u >> 16) & 1u)) >> 16);
}
__device__ __forceinline__ unsigned pack2bf(float a, float b) {
    return (unsigned)(unsigned short)f2bf(a) | ((unsigned)(unsigned short)f2bf(b) << 16);
}
__device__ __forceinline__ float bflo(unsigned u) { return __uint_as_float(u << 16); }
__device__ __forceinline__ float bfhi(unsigned u) { return __uint_as_float(u & 0xffff0000u); }

// ---- W prep + bucket-cursor init (one launch) ----
__global__ void k_prep(const float* __restrict__ W1, const float* __restrict__ W2,
                       short* __restrict__ w1t, short* __restrict__ w2t,
                       int* __restrict__ bcur, int nbuck) {
    int b = blockIdx.x;
    int t = threadIdx.x;
    if (b == gridDim.x - 1) {                 // last block: init bucket cursors
        for (int i = t; i < nbuck; i += 256) bcur[i] = i << CAPSH;
        return;
    }
    int i = b * 256 + t;                      // 96 blocks cover 24576 elems
    if (i < 128 * 128) {
        int n = i >> 7, k = i & 127;
        w1t[i] = f2bf(W1[k * 128 + n]);
    } else {
        int j = i - 128 * 128;
        int n = j >> 7, k = j & 127;
        w2t[j] = f2bf(W2[k * 64 + n]);
    }
}

// ---- partition edges into packed ebuf: entry = (src<<8) | (dst&255) ----
__global__ __launch_bounds__(256) void k_bucket(const int* __restrict__ src,
                                                const int* __restrict__ dst,
                                                int* __restrict__ bcur,
                                                unsigned* __restrict__ ebuf,
                                                int E, int nbuck) {
    __shared__ int sdst[4096];
    __shared__ int ssrc[4096];
    __shared__ int hist[512];
    __shared__ int base[512];
    int t = threadIdx.x;
    int e0 = blockIdx.x * 4096;
    for (int i = t; i < nbuck; i += 256) hist[i] = 0;
    for (int i = 0; i < 16; ++i) {                  // single global read
        int k = i * 256 + t;
        int e = e0 + k;
        sdst[k] = (e < E) ? dst[e] : -1;
        ssrc[k] = (e < E) ? src[e] : 0;
    }
    __syncthreads();
    for (int i = 0; i < 16; ++i) {                  // pass 1: LDS histogram
        int d = sdst[i * 256 + t];
        if (d >= 0) atomicAdd(&hist[d >> BSHIFT], 1);
    }
    __syncthreads();
    for (int b = t; b < nbuck; b += 256) {          // pass 2: reserve chunks
        int c = hist[b];
        base[b] = c ? atomicAdd(&bcur[b], c) : 0;
        hist[b] = 0;
    }
    __syncthreads();
    for (int i = 0; i < 16; ++i) {                  // pass 3: grouped writes
        int k = i * 256 + t;
        int d = sdst[k];
        if (d >= 0) {
            int bk = d >> BSHIFT;
            int off = atomicAdd(&hist[bk], 1);
            ebuf[base[bk] + off] = ((unsigned)ssrc[k] << BSHIFT) | (unsigned)(d & (BSIZE - 1));
        }
    }
}

// ---- per-bucket merged: LDS stage -> hist -> scan -> deg/dinv/row_ptr
//      -> LDS-cursor scatter -> csr4 = src ----
__global__ __launch_bounds__(BSIZE) void k_bcsr(const unsigned* __restrict__ ebuf,
                                                const int* __restrict__ bcur,
                                                int* __restrict__ deg,
                                                int* __restrict__ row_ptr,
                                                float* __restrict__ dinv,
                                                unsigned* __restrict__ csr4, int n) {
    __shared__ unsigned edges[CAP];    // 32 KB
    __shared__ int hist[BSIZE];
    __shared__ int s[BSIZE];
    __shared__ int cur[BSIZE];
    int b = blockIdx.x;
    int t = threadIdx.x;
    hist[t] = 0;
    __syncthreads();
    int base = b << CAPSH;
    int cnt  = bcur[b] - base;
    int lo = b << BSHIFT;
    for (int k = t; k < cnt; k += BSIZE) {          // stage + LDS hist
        unsigned e = ebuf[base + k];
        edges[k] = e;
        atomicAdd(&hist[e & (BSIZE - 1)], 1);
    }
    __syncthreads();
    int v = hist[t];
    s[t] = v;
    __syncthreads();
    for (int off = 1; off < BSIZE; off <<= 1) {     // inclusive scan (8 rounds)
        int add = (t >= off) ? s[t - off] : 0;
        __syncthreads();
        s[t] += add;
        __syncthreads();
    }
    int rp = base + s[t] - v;                       // padded-CSR offset
    cur[t] = rp;
    int node = lo + t;
    if (node < n) {
        deg[node]     = v;
        row_ptr[node] = rp;
        dinv[node]    = rsqrtf((float)(v + 1));
    }
    __syncthreads();
    for (int k = t; k < cnt; k += BSIZE) {          // scatter src -> csr4
        unsigned e = edges[k];
        int pos = atomicAdd(&cur[e & (BSIZE - 1)], 1);
        csr4[pos] = e >> BSHIFT;
    }
}

// ---- MFMA GEMM1: h1'[64rows,128] = dinv*(bf16(x) @ bf16(W1)) ----
#define LDP 136
__global__ __launch_bounds__(256) void k_gemm1(const float* __restrict__ x,
                                               const short* __restrict__ w1t,
                                               const float* __restrict__ dinv,
                                               short* __restrict__ h, int nrows) {
    __shared__ short xs[64 * LDP];
    __shared__ short wt[128 * LDP];
    int t = threadIdx.x;
    int row0 = blockIdx.x * 64;
    for (int i = 0; i < 16; ++i) {
        int idx = t + i * 256;
        int r = idx >> 5, c4 = idx & 31;
        float4 v = make_float4(0.f, 0.f, 0.f, 0.f);
        if (row0 + r < nrows) v = ((const float4*)x)[(size_t)(row0 + r) * 32 + c4];
        short4 o = make_short4(f2bf(v.x), f2bf(v.y), f2bf(v.z), f2bf(v.w));
        *(short4*)&xs[r * LDP + c4 * 4] = o;
    }
    for (int i = 0; i < 16; ++i) {
        int idx = t + i * 256;
        int n = idx >> 5, c4 = idx & 31;
        *(short4*)&wt[n * LDP + c4 * 4] = ((const short4*)w1t)[idx];
    }
    __syncthreads();
    int wave = t >> 6, lane = t & 63;
    int quad = lane >> 4, c = lane & 15;
    int m0 = wave * 16;
    f32x4 acc[8] = {};
    #pragma unroll
    for (int kc = 0; kc < 4; ++kc) {
        short8v a = *(const short8v*)&xs[(m0 + c) * LDP + kc * 32 + quad * 8];
        #pragma unroll
        for (int nt = 0; nt < 8; ++nt) {
            short8v b = *(const short8v*)&wt[(nt * 16 + c) * LDP + kc * 32 + quad * 8];
            acc[nt] = __builtin_amdgcn_mfma_f32_16x16x32_bf16(a, b, acc[nt], 0, 0, 0);
        }
    }
    #pragma unroll
    for (int r = 0; r < 4; ++r) {
        int row = row0 + m0 + quad * 4 + r;
        if (row < nrows) {
            float dr = dinv[row];                   // fold norm into stored row
            #pragma unroll
            for (int nt = 0; nt < 8; ++nt)
                h[(size_t)row * 128 + nt * 16 + c] = f2bf(acc[nt][r] * dr);
        }
    }
}

// ---- MFMA GEMM2: h2'[64rows,64] = dinv*(bf16(relu(aggb+b1)) @ bf16(W2)) ----
__global__ __launch_bounds__(256) void k_gemm2(const unsigned* __restrict__ aggb, // bf16x2
                                               const float* __restrict__ b1,
                                               const short* __restrict__ w2t,
                                               const float* __restrict__ dinv,
                                               short* __restrict__ h2, int nrows) {
    __shared__ short xs[64 * LDP];
    __shared__ short wt[64 * LDP];
    int t = threadIdx.x;
    int row0 = blockIdx.x * 64;
    for (int i = 0; i < 16; ++i) {                    // 64 rows x 64 bf16-pairs
        int idx = t + i * 256;
        int r = idx >> 6, cp = idx & 63;
        unsigned o = 0;
        if (row0 + r < nrows) {
            unsigned u = aggb[(size_t)(row0 + r) * 64 + cp];
            float2 bb = ((const float2*)b1)[cp];
            float vx = fmaxf(bflo(u) + bb.x, 0.f);
            float vy = fmaxf(bfhi(u) + bb.y, 0.f);
            o = pack2bf(vx, vy);
        }
        *(unsigned*)&xs[r * LDP + cp * 2] = o;
    }
    for (int i = 0; i < 8; ++i) {
        int idx = t + i * 256;
        int n = idx >> 5, c4 = idx & 31;
        *(short4*)&wt[n * LDP + c4 * 4] = ((const short4*)w2t)[idx];
    }
    __syncthreads();
    int wave = t >> 6, lane = t & 63;
    int quad = lane >> 4, c = lane & 15;
    int m0 = wave * 16;
    f32x4 acc[4] = {};
    #pragma unroll
    for (int kc = 0; kc < 4; ++kc) {
        short8v av = *(const short8v*)&xs[(m0 + c) * LDP + kc * 32 + quad * 8];
        #pragma unroll
        for (int nt = 0; nt < 4; ++nt) {
            short8v b = *(const short8v*)&wt[(nt * 16 + c) * LDP + kc * 32 + quad * 8];
            acc[nt] = __builtin_amdgcn_mfma_f32_16x16x32_bf16(av, b, acc[nt], 0, 0, 0);
        }
    }
    #pragma unroll
    for (int r = 0; r < 4; ++r) {
        int row = row0 + m0 + quad * 4 + r;
        if (row < nrows) {
            float dr = dinv[row];
            #pragma unroll
            for (int nt = 0; nt < 4; ++nt)
                h2[(size_t)row * 64 + nt * 16 + c] = f2bf(acc[nt][r] * dr);
        }
    }
}

// pull 128 feats: aggb[i] = bf16( dinv[i] * (h'[i] + sum_nbr h'[s]) ).
// One wave/node; node range [i0, n1) — launched as 4 quarter-range
// dispatches for profiling visibility (work-identical to one dispatch).
__global__ __launch_bounds__(256) void k_pull128(const unsigned short* __restrict__ h,
                                                 const int* __restrict__ row_ptr,
                                                 const int* __restrict__ deg,
                                                 const unsigned* __restrict__ csr4,
                                                 const float* __restrict__ dinv,
                                                 unsigned* __restrict__ aggb,
                                                 int i0, int n1) {
    int wave = (blockIdx.x * 256 + threadIdx.x) >> 6;
    int lane = threadIdx.x & 63;
    int i = i0 + wave;
    if (i >= n1) return;
    i = __builtin_amdgcn_readfirstlane(i);
    float2 acc;
    {
        unsigned u = ((const unsigned*)(h + (size_t)i * 128))[lane];   // self
        acc.x = bflo(u);
        acc.y = bfhi(u);
    }
    int beg = row_ptr[i];
    int cnt = deg[i];
    int k = 0;
    for (; k + 8 <= cnt; k += 8) {
        unsigned sid[8];
        unsigned g[8];
        #pragma unroll
        for (int j = 0; j < 8; ++j) sid[j] = csr4[beg + k + j];
        #pragma unroll
        for (int j = 0; j < 8; ++j)
            g[j] = ((const unsigned*)(h + (size_t)sid[j] * 128))[lane];
        #pragma unroll
        for (int j = 0; j < 8; ++j) {
            acc.x += bflo(g[j]);
            acc.y += bfhi(g[j]);
        }
    }
    for (; k < cnt; ++k) {
        unsigned sid = csr4[beg + k];
        unsigned g = ((const unsigned*)(h + (size_t)sid * 128))[lane];
        acc.x += bflo(g);
        acc.y += bfhi(g);
    }
    float di = dinv[i];
    aggb[(size_t)i * 64 + lane] = pack2bf(acc.x * di, acc.y * di);   // plain store:
                                                                     // gemm2 re-reads
}

// pull 64 feats, TWO nodes per wave: 32-lane half-waves, uint granule.
// Each gather instruction covers 2 rows (2 x 128 B) -> 2x rows in flight.
// out[i] = dinv[i]*(h'[i] + sum h'[s]) + b2; NT store (never re-read).
__global__ __launch_bounds__(256) void k_pull64(const unsigned short* __restrict__ h,
                                                const int* __restrict__ row_ptr,
                                                const int* __restrict__ deg,
                                                const unsigned* __restrict__ csr4,
                                                const float* __restrict__ dinv,
                                                const float* __restrict__ b2,
                                                float* __restrict__ out, int n) {
    int wave = (blockIdx.x * 256 + threadIdx.x) >> 6;
    int lane = threadIdx.x & 63;
    int half = lane >> 5;                 // which of the wave's 2 nodes
    int lh   = lane & 31;                 // uint index: feats 2lh, 2lh+1
    int node = wave * 2 + half;
    bool alive = node < n;
    int nn = alive ? node : 0;            // safe row for dead half
    int beg = row_ptr[nn];
    int cnt = alive ? deg[nn] : 0;
    float2 acc;
    {
        unsigned u = ((const unsigned*)(h + (size_t)nn * 64))[lh];   // self (128B/half)
        acc.x = bflo(u);
        acc.y = bfhi(u);
    }
    int k = 0;
    for (; k + 8 <= cnt; k += 8) {        // per-half trip counts, exec-masked
        unsigned sid[8];
        unsigned g[8];
        #pragma unroll
        for (int j = 0; j < 8; ++j) sid[j] = csr4[beg + k + j];
        #pragma unroll
        for (int j = 0; j < 8; ++j)
            g[j] = ((const unsigned*)(h + (size_t)sid[j] * 64))[lh];
        #pragma unroll
        for (int j = 0; j < 8; ++j) {
            acc.x += bflo(g[j]);
            acc.y += bfhi(g[j]);
        }
    }
    for (; k < cnt; ++k) {
        unsigned sid = csr4[beg + k];
        unsigned g = ((const unsigned*)(h + (size_t)sid * 64))[lh];
        acc.x += bflo(g);
        acc.y += bfhi(g);
    }
    if (alive) {
        float di = dinv[nn];
        float2 bb = ((const float2*)b2)[lh];
        f32x2 o;
        o[0] = acc.x * di + bb.x;
        o[1] = acc.y * di + bb.y;
        __builtin_nontemporal_store(o, (f32x2*)&out[(size_t)nn * 64 + lh * 2]);
    }
}

extern "C" void kernel_launch(void* const* d_in, const int* in_sizes, int n_in,
                              void* d_out, int out_size, void* d_ws, size_t ws_size,
                              hipStream_t stream) {
    const float* x  = (const float*)d_in[0];
    const int*   ei = (const int*)d_in[1];
    const float* W1 = (const float*)d_in[2];
    const float* b1 = (const float*)d_in[3];
    const float* W2 = (const float*)d_in[4];
    const float* b2 = (const float*)d_in[5];
    float* out = (float*)d_out;

    const int N = in_sizes[0] / 128;
    const int E = in_sizes[1] / 2;
    const int* src = ei;
    const int* dst = ei + E;
    const int nbuck = (N + BSIZE - 1) >> BSHIFT;        // 391 for N=100000
    const size_t capE = (size_t)nbuck << CAPSH;         // padded edge capacity

    float* dinv     = (float*)d_ws;                     // N
    int*   deg      = (int*)(dinv + N);                 // N
    int*   row_ptr  = deg + N;                          // N
    int*   bcur     = row_ptr + N;                      // 512
    short* w1t      = (short*)(bcur + 512);             // 128*128
    short* w2t      = w1t + 128 * 128;                  // 64*128
    unsigned* csr4  = (unsigned*)(w2t + 64 * 128);      // capE (12.8 MB)
    short* bufH     = (short*)(csr4 + capE);            // N*128 bf16 (h1')
    short* bufH2    = bufH + (size_t)N * 128;           // N*64  bf16 (h2')
    unsigned* aggb  = (unsigned*)(bufH2 + (size_t)N * 64); // N*64 bf16x2 (agg1)
    unsigned* ebuf  = (unsigned*)bufH2;                 // capE uints; aliases
                                                        // bufH2+aggb (ebuf dead
                                                        // before their writes)

    const int ntile = (E + 4095) / 4096;
    const int nwv64 = (N + 1) / 2;                      // pull64 waves (2 nodes each)
    const int Nq = (N + 3) / 4;                         // pull128 quarter range

    // ---- weight prep + bucket cursor init ----
    k_prep<<<97, 256, 0, stream>>>(W1, W2, w1t, w2t, bcur, nbuck);

    // ---- bucketed CSR build (per-node atomics all in LDS) ----
    k_bucket<<<ntile, 256, 0, stream>>>(src, dst, bcur, ebuf, E, nbuck);
    k_bcsr<<<nbuck, BSIZE, 0, stream>>>(ebuf, bcur, deg, row_ptr, dinv, csr4, N);

    // ---- layer 1 ----
    k_gemm1<<<(N + 63) / 64, 256, 0, stream>>>(x, w1t, dinv, bufH, N);
    for (int q = 0; q < 4; ++q) {                       // 4 quarter-range dispatches
        int s0 = q * Nq;
        int e0 = (s0 + Nq < N) ? (s0 + Nq) : N;
        if (s0 >= e0) break;
        k_pull128<<<(e0 - s0 + 3) / 4, 256, 0, stream>>>(
            (const unsigned short*)bufH, row_ptr, deg, csr4, dinv, aggb, s0, e0);
    }

    // ---- layer 2 ----
    k_gemm2<<<(N + 63) / 64, 256, 0, stream>>>(aggb, b1, w2t, dinv, bufH2, N);
    k_pull64<<<(nwv64 + 3) / 4, 256, 0, stream>>>((const unsigned short*)bufH2, row_ptr, deg, csr4, dinv, b2, out, N);
}

// Round 19
// 284.350 us; speedup vs baseline: 1.0565x; 1.0565x over previous
//
#include <hip/hip_runtime.h>
#include <hip/hip_bf16.h>

// GCN 2-layer forward, fp32 I/O. dinv folded into stored rows:
//   h1' = dinv * (x @ W1),  agg1 = dinv * (h1'[i] + sum_nbr h1'[s])
//   h2' = dinv * (relu(agg1+b1) @ W2),  out = dinv * (h2'[i] + sum h2'[s]) + b2
// so pull kernels are pure gather+add (no per-edge norm, no dinv reads).
// Packed 4B edge records; fixed-capacity bucketed CSR build with all
// per-node atomics in LDS; bf16 h/agg storage; MFMA bf16 GEMMs.
//
// ROUND 19: round-18's diagnostic split surfaced k_pull64 as the true #2
// (46 us, FETCH 83 MB == its compulsory floor, but only 2.4 TB/s vs the
// 3.75 TB/s fabric ceiling -> concurrency-limited: half the waves of
// pull128 with the same 2 KB in flight each). Changes:
//  * pull128 back to ONE dispatch (the 4-way split cost ~14 us of
//    launch/drain overhead; its diagnostic job is done).
//  * k_pull64 main loop deepened 8 -> 16 edges in flight per half-wave
//    (4 KB/wave in flight, matching pull128's aggregate) to close its
//    ~16 us gap to the 30 us bandwidth floor.
// Pipeline:
//  1) k_prep: W1,W2 -> bf16 transposed; bcur[b] = b*CAP (looped init)
//  2) k_bucket: partition packed {src,dloc} by dst>>8 into ebuf
//  3) k_bcsr:  per-bucket LDS stage -> hist -> scan -> deg/dinv/row_ptr
//              -> LDS-cursor scatter -> csr4 = src
//  4) h1' = dinv*(x @ W1) -> bf16                  (k_gemm1, MFMA)
//  5) aggb = dinv*(self+gather-sum of h1') -> bf16 (k_pull128)
//  6) h2' = dinv*(relu(aggb+b1) @ W2) -> bf16      (k_gemm2, MFMA)
//  7) out = dinv*(self+gather-sum of h2') + b2     (k_pull64, 2 nodes/wave)

typedef short short8v __attribute__((ext_vector_type(8)));   // 8 bf16 (4 VGPRs)
typedef float f32x4   __attribute__((ext_vector_type(4)));   // MFMA acc
typedef float f32x2   __attribute__((ext_vector_type(2)));   // NT out store

#define BSHIFT 8           // bucket = dst >> 8 (span 256 nodes)
#define BSIZE  256
#define CAPSH  13          // per-bucket capacity 8192 (mean 4352, +58 sigma)
#define CAP    (1 << CAPSH)

// RNE fp32 -> bf16 (finite inputs)
__device__ __forceinline__ short f2bf(float f) {
    unsigned u = __float_as_uint(f);
    return (short)((u + 0x7fffu + ((u >> 16) & 1u)) >> 16);
}
__device__ __forceinline__ unsigned pack2bf(float a, float b) {
    return (unsigned)(unsigned short)f2bf(a) | ((unsigned)(unsigned short)f2bf(b) << 16);
}
__device__ __forceinline__ float bflo(unsigned u) { return __uint_as_float(u << 16); }
__device__ __forceinline__ float bfhi(unsigned u) { return __uint_as_float(u & 0xffff0000u); }

// ---- W prep + bucket-cursor init (one launch) ----
__global__ void k_prep(const float* __restrict__ W1, const float* __restrict__ W2,
                       short* __restrict__ w1t, short* __restrict__ w2t,
                       int* __restrict__ bcur, int nbuck) {
    int b = blockIdx.x;
    int t = threadIdx.x;
    if (b == gridDim.x - 1) {                 // last block: init bucket cursors
        for (int i = t; i < nbuck; i += 256) bcur[i] = i << CAPSH;
        return;
    }
    int i = b * 256 + t;                      // 96 blocks cover 24576 elems
    if (i < 128 * 128) {
        int n = i >> 7, k = i & 127;
        w1t[i] = f2bf(W1[k * 128 + n]);
    } else {
        int j = i - 128 * 128;
        int n = j >> 7, k = j & 127;
        w2t[j] = f2bf(W2[k * 64 + n]);
    }
}

// ---- partition edges into packed ebuf: entry = (src<<8) | (dst&255) ----
__global__ __launch_bounds__(256) void k_bucket(const int* __restrict__ src,
                                                const int* __restrict__ dst,
                                                int* __restrict__ bcur,
                                                unsigned* __restrict__ ebuf,
                                                int E, int nbuck) {
    __shared__ int sdst[4096];
    __shared__ int ssrc[4096];
    __shared__ int hist[512];
    __shared__ int base[512];
    int t = threadIdx.x;
    int e0 = blockIdx.x * 4096;
    for (int i = t; i < nbuck; i += 256) hist[i] = 0;
    for (int i = 0; i < 16; ++i) {                  // single global read
        int k = i * 256 + t;
        int e = e0 + k;
        sdst[k] = (e < E) ? dst[e] : -1;
        ssrc[k] = (e < E) ? src[e] : 0;
    }
    __syncthreads();
    for (int i = 0; i < 16; ++i) {                  // pass 1: LDS histogram
        int d = sdst[i * 256 + t];
        if (d >= 0) atomicAdd(&hist[d >> BSHIFT], 1);
    }
    __syncthreads();
    for (int b = t; b < nbuck; b += 256) {          // pass 2: reserve chunks
        int c = hist[b];
        base[b] = c ? atomicAdd(&bcur[b], c) : 0;
        hist[b] = 0;
    }
    __syncthreads();
    for (int i = 0; i < 16; ++i) {                  // pass 3: grouped writes
        int k = i * 256 + t;
        int d = sdst[k];
        if (d >= 0) {
            int bk = d >> BSHIFT;
            int off = atomicAdd(&hist[bk], 1);
            ebuf[base[bk] + off] = ((unsigned)ssrc[k] << BSHIFT) | (unsigned)(d & (BSIZE - 1));
        }
    }
}

// ---- per-bucket merged: LDS stage -> hist -> scan -> deg/dinv/row_ptr
//      -> LDS-cursor scatter -> csr4 = src ----
__global__ __launch_bounds__(BSIZE) void k_bcsr(const unsigned* __restrict__ ebuf,
                                                const int* __restrict__ bcur,
                                                int* __restrict__ deg,
                                                int* __restrict__ row_ptr,
                                                float* __restrict__ dinv,
                                                unsigned* __restrict__ csr4, int n) {
    __shared__ unsigned edges[CAP];    // 32 KB
    __shared__ int hist[BSIZE];
    __shared__ int s[BSIZE];
    __shared__ int cur[BSIZE];
    int b = blockIdx.x;
    int t = threadIdx.x;
    hist[t] = 0;
    __syncthreads();
    int base = b << CAPSH;
    int cnt  = bcur[b] - base;
    int lo = b << BSHIFT;
    for (int k = t; k < cnt; k += BSIZE) {          // stage + LDS hist
        unsigned e = ebuf[base + k];
        edges[k] = e;
        atomicAdd(&hist[e & (BSIZE - 1)], 1);
    }
    __syncthreads();
    int v = hist[t];
    s[t] = v;
    __syncthreads();
    for (int off = 1; off < BSIZE; off <<= 1) {     // inclusive scan (8 rounds)
        int add = (t >= off) ? s[t - off] : 0;
        __syncthreads();
        s[t] += add;
        __syncthreads();
    }
    int rp = base + s[t] - v;                       // padded-CSR offset
    cur[t] = rp;
    int node = lo + t;
    if (node < n) {
        deg[node]     = v;
        row_ptr[node] = rp;
        dinv[node]    = rsqrtf((float)(v + 1));
    }
    __syncthreads();
    for (int k = t; k < cnt; k += BSIZE) {          // scatter src -> csr4
        unsigned e = edges[k];
        int pos = atomicAdd(&cur[e & (BSIZE - 1)], 1);
        csr4[pos] = e >> BSHIFT;
    }
}

// ---- MFMA GEMM1: h1'[64rows,128] = dinv*(bf16(x) @ bf16(W1)) ----
#define LDP 136
__global__ __launch_bounds__(256) void k_gemm1(const float* __restrict__ x,
                                               const short* __restrict__ w1t,
                                               const float* __restrict__ dinv,
                                               short* __restrict__ h, int nrows) {
    __shared__ short xs[64 * LDP];
    __shared__ short wt[128 * LDP];
    int t = threadIdx.x;
    int row0 = blockIdx.x * 64;
    for (int i = 0; i < 16; ++i) {
        int idx = t + i * 256;
        int r = idx >> 5, c4 = idx & 31;
        float4 v = make_float4(0.f, 0.f, 0.f, 0.f);
        if (row0 + r < nrows) v = ((const float4*)x)[(size_t)(row0 + r) * 32 + c4];
        short4 o = make_short4(f2bf(v.x), f2bf(v.y), f2bf(v.z), f2bf(v.w));
        *(short4*)&xs[r * LDP + c4 * 4] = o;
    }
    for (int i = 0; i < 16; ++i) {
        int idx = t + i * 256;
        int n = idx >> 5, c4 = idx & 31;
        *(short4*)&wt[n * LDP + c4 * 4] = ((const short4*)w1t)[idx];
    }
    __syncthreads();
    int wave = t >> 6, lane = t & 63;
    int quad = lane >> 4, c = lane & 15;
    int m0 = wave * 16;
    f32x4 acc[8] = {};
    #pragma unroll
    for (int kc = 0; kc < 4; ++kc) {
        short8v a = *(const short8v*)&xs[(m0 + c) * LDP + kc * 32 + quad * 8];
        #pragma unroll
        for (int nt = 0; nt < 8; ++nt) {
            short8v b = *(const short8v*)&wt[(nt * 16 + c) * LDP + kc * 32 + quad * 8];
            acc[nt] = __builtin_amdgcn_mfma_f32_16x16x32_bf16(a, b, acc[nt], 0, 0, 0);
        }
    }
    #pragma unroll
    for (int r = 0; r < 4; ++r) {
        int row = row0 + m0 + quad * 4 + r;
        if (row < nrows) {
            float dr = dinv[row];                   // fold norm into stored row
            #pragma unroll
            for (int nt = 0; nt < 8; ++nt)
                h[(size_t)row * 128 + nt * 16 + c] = f2bf(acc[nt][r] * dr);
        }
    }
}

// ---- MFMA GEMM2: h2'[64rows,64] = dinv*(bf16(relu(aggb+b1)) @ bf16(W2)) ----
__global__ __launch_bounds__(256) void k_gemm2(const unsigned* __restrict__ aggb, // bf16x2
                                               const float* __restrict__ b1,
                                               const short* __restrict__ w2t,
                                               const float* __restrict__ dinv,
                                               short* __restrict__ h2, int nrows) {
    __shared__ short xs[64 * LDP];
    __shared__ short wt[64 * LDP];
    int t = threadIdx.x;
    int row0 = blockIdx.x * 64;
    for (int i = 0; i < 16; ++i) {                    // 64 rows x 64 bf16-pairs
        int idx = t + i * 256;
        int r = idx >> 6, cp = idx & 63;
        unsigned o = 0;
        if (row0 + r < nrows) {
            unsigned u = aggb[(size_t)(row0 + r) * 64 + cp];
            float2 bb = ((const float2*)b1)[cp];
            float vx = fmaxf(bflo(u) + bb.x, 0.f);
            float vy = fmaxf(bfhi(u) + bb.y, 0.f);
            o = pack2bf(vx, vy);
        }
        *(unsigned*)&xs[r * LDP + cp * 2] = o;
    }
    for (int i = 0; i < 8; ++i) {
        int idx = t + i * 256;
        int n = idx >> 5, c4 = idx & 31;
        *(short4*)&wt[n * LDP + c4 * 4] = ((const short4*)w2t)[idx];
    }
    __syncthreads();
    int wave = t >> 6, lane = t & 63;
    int quad = lane >> 4, c = lane & 15;
    int m0 = wave * 16;
    f32x4 acc[4] = {};
    #pragma unroll
    for (int kc = 0; kc < 4; ++kc) {
        short8v av = *(const short8v*)&xs[(m0 + c) * LDP + kc * 32 + quad * 8];
        #pragma unroll
        for (int nt = 0; nt < 4; ++nt) {
            short8v b = *(const short8v*)&wt[(nt * 16 + c) * LDP + kc * 32 + quad * 8];
            acc[nt] = __builtin_amdgcn_mfma_f32_16x16x32_bf16(av, b, acc[nt], 0, 0, 0);
        }
    }
    #pragma unroll
    for (int r = 0; r < 4; ++r) {
        int row = row0 + m0 + quad * 4 + r;
        if (row < nrows) {
            float dr = dinv[row];
            #pragma unroll
            for (int nt = 0; nt < 4; ++nt)
                h2[(size_t)row * 64 + nt * 16 + c] = f2bf(acc[nt][r] * dr);
        }
    }
}

// pull 128 feats: aggb[i] = bf16( dinv[i] * (h'[i] + sum_nbr h'[s]) ).
// One wave/node; pure gather+add inner loop (csr reads on scalar path).
// At the random-256B fabric roofline (FETCH == compulsory floor) — closed.
__global__ __launch_bounds__(256) void k_pull128(const unsigned short* __restrict__ h,
                                                 const int* __restrict__ row_ptr,
                                                 const int* __restrict__ deg,
                                                 const unsigned* __restrict__ csr4,
                                                 const float* __restrict__ dinv,
                                                 unsigned* __restrict__ aggb, int n) {
    int wave = (blockIdx.x * 256 + threadIdx.x) >> 6;
    int lane = threadIdx.x & 63;
    if (wave >= n) return;
    int i = __builtin_amdgcn_readfirstlane(wave);
    float2 acc;
    {
        unsigned u = ((const unsigned*)(h + (size_t)i * 128))[lane];   // self
        acc.x = bflo(u);
        acc.y = bfhi(u);
    }
    int beg = row_ptr[i];
    int cnt = deg[i];
    int k = 0;
    for (; k + 8 <= cnt; k += 8) {
        unsigned sid[8];
        unsigned g[8];
        #pragma unroll
        for (int j = 0; j < 8; ++j) sid[j] = csr4[beg + k + j];
        #pragma unroll
        for (int j = 0; j < 8; ++j)
            g[j] = ((const unsigned*)(h + (size_t)sid[j] * 128))[lane];
        #pragma unroll
        for (int j = 0; j < 8; ++j) {
            acc.x += bflo(g[j]);
            acc.y += bfhi(g[j]);
        }
    }
    for (; k < cnt; ++k) {
        unsigned sid = csr4[beg + k];
        unsigned g = ((const unsigned*)(h + (size_t)sid * 128))[lane];
        acc.x += bflo(g);
        acc.y += bfhi(g);
    }
    float di = dinv[i];
    aggb[(size_t)i * 64 + lane] = pack2bf(acc.x * di, acc.y * di);   // plain store:
                                                                     // gemm2 re-reads
}

// pull 64 feats, TWO nodes per wave, 16-deep main loop: 32-lane
// half-waves, uint granule; 16 idx + 16 gathers in flight (4 KB/wave,
// matching pull128's per-wave in-flight bytes at half the wave count).
// out[i] = dinv[i]*(h'[i] + sum h'[s]) + b2; NT store (never re-read).
__global__ __launch_bounds__(256) void k_pull64(const unsigned short* __restrict__ h,
                                                const int* __restrict__ row_ptr,
                                                const int* __restrict__ deg,
                                                const unsigned* __restrict__ csr4,
                                                const float* __restrict__ dinv,
                                                const float* __restrict__ b2,
                                                float* __restrict__ out, int n) {
    int wave = (blockIdx.x * 256 + threadIdx.x) >> 6;
    int lane = threadIdx.x & 63;
    int half = lane >> 5;                 // which of the wave's 2 nodes
    int lh   = lane & 31;                 // uint index: feats 2lh, 2lh+1
    int node = wave * 2 + half;
    bool alive = node < n;
    int nn = alive ? node : 0;            // safe row for dead half
    int beg = row_ptr[nn];
    int cnt = alive ? deg[nn] : 0;
    float2 acc;
    {
        unsigned u = ((const unsigned*)(h + (size_t)nn * 64))[lh];   // self (128B/half)
        acc.x = bflo(u);
        acc.y = bfhi(u);
    }
    int k = 0;
    for (; k + 16 <= cnt; k += 16) {      // 16 rows in flight per half-wave
        unsigned sid[16];
        unsigned g[16];
        #pragma unroll
        for (int j = 0; j < 16; ++j) sid[j] = csr4[beg + k + j];
        #pragma unroll
        for (int j = 0; j < 16; ++j)
            g[j] = ((const unsigned*)(h + (size_t)sid[j] * 64))[lh];
        #pragma unroll
        for (int j = 0; j < 16; ++j) {
            acc.x += bflo(g[j]);
            acc.y += bfhi(g[j]);
        }
    }
    for (; k + 8 <= cnt; k += 8) {
        unsigned sid[8];
        unsigned g[8];
        #pragma unroll
        for (int j = 0; j < 8; ++j) sid[j] = csr4[beg + k + j];
        #pragma unroll
        for (int j = 0; j < 8; ++j)
            g[j] = ((const unsigned*)(h + (size_t)sid[j] * 64))[lh];
        #pragma unroll
        for (int j = 0; j < 8; ++j) {
            acc.x += bflo(g[j]);
            acc.y += bfhi(g[j]);
        }
    }
    for (; k < cnt; ++k) {
        unsigned sid = csr4[beg + k];
        unsigned g = ((const unsigned*)(h + (size_t)sid * 64))[lh];
        acc.x += bflo(g);
        acc.y += bfhi(g);
    }
    if (alive) {
        float di = dinv[nn];
        float2 bb = ((const float2*)b2)[lh];
        f32x2 o;
        o[0] = acc.x * di + bb.x;
        o[1] = acc.y * di + bb.y;
        __builtin_nontemporal_store(o, (f32x2*)&out[(size_t)nn * 64 + lh * 2]);
    }
}

extern "C" void kernel_launch(void* const* d_in, const int* in_sizes, int n_in,
                              void* d_out, int out_size, void* d_ws, size_t ws_size,
                              hipStream_t stream) {
    const float* x  = (const float*)d_in[0];
    const int*   ei = (const int*)d_in[1];
    const float* W1 = (const float*)d_in[2];
    const float* b1 = (const float*)d_in[3];
    const float* W2 = (const float*)d_in[4];
    const float* b2 = (const float*)d_in[5];
    float* out = (float*)d_out;

    const int N = in_sizes[0] / 128;
    const int E = in_sizes[1] / 2;
    const int* src = ei;
    const int* dst = ei + E;
    const int nbuck = (N + BSIZE - 1) >> BSHIFT;        // 391 for N=100000
    const size_t capE = (size_t)nbuck << CAPSH;         // padded edge capacity

    float* dinv     = (float*)d_ws;                     // N
    int*   deg      = (int*)(dinv + N);                 // N
    int*   row_ptr  = deg + N;                          // N
    int*   bcur     = row_ptr + N;                      // 512
    short* w1t      = (short*)(bcur + 512);             // 128*128
    short* w2t      = w1t + 128 * 128;                  // 64*128
    unsigned* csr4  = (unsigned*)(w2t + 64 * 128);      // capE (12.8 MB)
    short* bufH     = (short*)(csr4 + capE);            // N*128 bf16 (h1')
    short* bufH2    = bufH + (size_t)N * 128;           // N*64  bf16 (h2')
    unsigned* aggb  = (unsigned*)(bufH2 + (size_t)N * 64); // N*64 bf16x2 (agg1)
    unsigned* ebuf  = (unsigned*)bufH2;                 // capE uints; aliases
                                                        // bufH2+aggb (ebuf dead
                                                        // before their writes)

    const int ntile = (E + 4095) / 4096;
    const int nwv64 = (N + 1) / 2;                      // pull64 waves (2 nodes each)

    // ---- weight prep + bucket cursor init ----
    k_prep<<<97, 256, 0, stream>>>(W1, W2, w1t, w2t, bcur, nbuck);

    // ---- bucketed CSR build (per-node atomics all in LDS) ----
    k_bucket<<<ntile, 256, 0, stream>>>(src, dst, bcur, ebuf, E, nbuck);
    k_bcsr<<<nbuck, BSIZE, 0, stream>>>(ebuf, bcur, deg, row_ptr, dinv, csr4, N);

    // ---- layer 1 ----
    k_gemm1<<<(N + 63) / 64, 256, 0, stream>>>(x, w1t, dinv, bufH, N);
    k_pull128<<<(N + 3) / 4, 256, 0, stream>>>((const unsigned short*)bufH, row_ptr, deg, csr4, dinv, aggb, N);

    // ---- layer 2 ----
    k_gemm2<<<(N + 63) / 64, 256, 0, stream>>>(aggb, b1, w2t, dinv, bufH2, N);
    k_pull64<<<(nwv64 + 3) / 4, 256, 0, stream>>>((const unsigned short*)bufH2, row_ptr, deg, csr4, dinv, b2, out, N);
}